// Round 12
// baseline (136.378 us; speedup 1.0000x reference)
//
#include <hip/hip_runtime.h>

#define EMB   300
#define QLEN  256
#define DLEN  8192
#define KTOP  5
#define STR   320      // bf16 row stride (elements)
#define STRB  640      // bf16 row stride (bytes)

typedef __attribute__((ext_vector_type(8))) short short8v;
typedef __attribute__((ext_vector_type(4))) float f32x4;

__device__ inline float bf2f(short u) {
    return __uint_as_float(((unsigned int)(unsigned short)u) << 16);
}
__device__ inline short f2bf(float f) {
    unsigned int x = __float_as_uint(f);
    unsigned int r = x + 0x7fffu + ((x >> 16) & 1u);  // RNE
    return (short)(r >> 16);
}
__device__ inline void gload_lds16(const void* g, void* l) {
    __builtin_amdgcn_global_load_lds((const __attribute__((address_space(1))) void*)g,
                                     (__attribute__((address_space(3))) void*)l, 16, 0, 0);
}
// LDS swizzle involution on [rows][128B] tiles: XOR 16B-slot bits (4-6) with row&7
__device__ inline int swz128(int a) { return a ^ (((a >> 7) & 7) << 4); }

// ---------------- top-5 insert ----------------
#define INSERT5(arr, v)                                                          \
    if ((v) > arr[4]) {                                                          \
        arr[4] = (v);                                                            \
        if (arr[4] > arr[3]) { float t_ = arr[4]; arr[4] = arr[3]; arr[3] = t_; }\
        if (arr[3] > arr[2]) { float t_ = arr[3]; arr[3] = arr[2]; arr[2] = t_; }\
        if (arr[2] > arr[1]) { float t_ = arr[2]; arr[2] = arr[1]; arr[1] = t_; }\
        if (arr[1] > arr[0]) { float t_ = arr[1]; arr[1] = arr[0]; arr[0] = t_; }\
    }

// ====== prep: gathers (+row sumsq), filter casts, and convssq zeroing, one launch ======
// blocks [0,4646): wave-per-row work; blocks [4646,4679): zero convssq (33280 floats)
struct PrepArgs {
    const float* embeds;
    const int* toks[3]; short* out[3]; float* ssq[3]; int rows[3];
    const float* filt[2]; short* fout[2];
    float* convssq;
};

__global__ void prep(PrepArgs pa) {
    if (blockIdx.x >= 4646) {
        int idx = (blockIdx.x - 4646) * 256 + threadIdx.x;
        if (idx < 8320) {
            float4 z = {0.f, 0.f, 0.f, 0.f};
            *(float4*)(pa.convssq + idx * 4) = z;
        }
        return;
    }
    int W = blockIdx.x * 4 + (threadIdx.x >> 6);
    int lane = threadIdx.x & 63;
    int e0 = lane * 8;
    if (W < 16664) {
        int s, r;
        if (W < 264) { s = 0; r = W; }
        else if (W < 8464) { s = 1; r = W - 264; }
        else { s = 2; r = W - 8464; }
        int rows = pa.rows[s];
        short8v ov = {0, 0, 0, 0, 0, 0, 0, 0};
        float sum = 0.f;
        if (r < rows && e0 < 300) {
            const float* src = pa.embeds + (long)pa.toks[s][r] * EMB;
            float4 f0 = *(const float4*)(src + e0);
            ov[0] = f2bf(f0.x); ov[1] = f2bf(f0.y); ov[2] = f2bf(f0.z); ov[3] = f2bf(f0.w);
            sum = f0.x * f0.x + f0.y * f0.y + f0.z * f0.z + f0.w * f0.w;
            if (e0 < 296) {
                float4 f1 = *(const float4*)(src + e0 + 4);
                ov[4] = f2bf(f1.x); ov[5] = f2bf(f1.y); ov[6] = f2bf(f1.z); ov[7] = f2bf(f1.w);
                sum += f1.x * f1.x + f1.y * f1.y + f1.z * f1.z + f1.w * f1.w;
            }
        }
        if (e0 < STR) *(short8v*)(pa.out[s] + (long)r * STR + e0) = ov;
        #pragma unroll
        for (int off = 32; off > 0; off >>= 1) sum += __shfl_down(sum, off, 64);
        if (lane == 0 && r < rows) pa.ssq[s][r] = sum;
    } else {
        int w2 = W - 16664;
        int s = (w2 < 768) ? 0 : 1;
        int R = (s == 0) ? w2 : w2 - 768;
        int o = (s == 0) ? (R >> 1) : (R / 3);
        short8v ov = {0, 0, 0, 0, 0, 0, 0, 0};
        if (o < EMB && e0 < 300) {
            const float* src = pa.filt[s] + (long)R * EMB;
            float4 f0 = *(const float4*)(src + e0);
            ov[0] = f2bf(f0.x); ov[1] = f2bf(f0.y); ov[2] = f2bf(f0.z); ov[3] = f2bf(f0.w);
            if (e0 < 296) {
                float4 f1 = *(const float4*)(src + e0 + 4);
                ov[4] = f2bf(f1.x); ov[5] = f2bf(f1.y); ov[6] = f2bf(f1.z); ov[7] = f2bf(f1.w);
            }
        }
        if (e0 < STR) *(short8v*)(pa.fout[s] + (long)R * STR + e0) = ov;
    }
}

// ============ single-buffer BK=64 MFMA GEMM core, 64x128 tile, 4 waves (2x2 of 32x64) ======
#define GEMM_PRELUDE64                                                        \
    int tid = threadIdx.x, lane = tid & 63, w = tid >> 6;                     \
    int wr = w >> 1, wc = w & 1;                                              \
    int arow[2], acol[2], brow[4], bcol[4];                                   \
    _Pragma("unroll")                                                         \
    for (int i_ = 0; i_ < 2; ++i_) {                                          \
        int lg_ = swz128(w * 2048 + i_ * 1024 + lane * 16);                   \
        arow[i_] = lg_ >> 7; acol[i_] = lg_ & 127;                            \
    }                                                                         \
    _Pragma("unroll")                                                         \
    for (int i_ = 0; i_ < 4; ++i_) {                                          \
        int lg_ = swz128(w * 4096 + i_ * 1024 + lane * 16);                   \
        brow[i_] = lg_ >> 7; bcol[i_] = lg_ & 127;                            \
    }

#define STAGE64(t) do { int kb_ = (t) * 128;                                  \
    _Pragma("unroll")                                                         \
    for (int i_ = 0; i_ < 2; ++i_)                                            \
        gload_lds16(Ab + (size_t)arow[i_] * STRB + kb_ + acol[i_],            \
                    AsB + w * 2048 + i_ * 1024);                              \
    _Pragma("unroll")                                                         \
    for (int i_ = 0; i_ < 4; ++i_)                                            \
        gload_lds16(Bb + (size_t)brow[i_] * ldbB + kb_ + bcol[i_],            \
                    BsB + w * 4096 + i_ * 1024);                              \
    } while (0)

#define COMPUTE64 do {                                                        \
    _Pragma("unroll")                                                         \
    for (int h_ = 0; h_ < 2; ++h_) {                                          \
        short8v a_[2], b_[4];                                                 \
        _Pragma("unroll")                                                     \
        for (int f_ = 0; f_ < 2; ++f_) {                                      \
            int la_ = (wr * 32 + f_ * 16 + (lane & 15)) * 128                 \
                      + ((lane >> 4) << 4) + h_ * 64;                         \
            a_[f_] = *(const short8v*)(AsB + swz128(la_));                    \
        }                                                                     \
        _Pragma("unroll")                                                     \
        for (int f_ = 0; f_ < 4; ++f_) {                                      \
            int lb_ = (wc * 64 + f_ * 16 + (lane & 15)) * 128                 \
                      + ((lane >> 4) << 4) + h_ * 64;                         \
            b_[f_] = *(const short8v*)(BsB + swz128(lb_));                    \
        }                                                                     \
        _Pragma("unroll")                                                     \
        for (int mf_ = 0; mf_ < 2; ++mf_)                                     \
            _Pragma("unroll")                                                 \
            for (int nf_ = 0; nf_ < 4; ++nf_)                                 \
                acc[mf_][nf_] = __builtin_amdgcn_mfma_f32_16x16x32_bf16(      \
                    a_[mf_], b_[nf_], acc[mf_][nf_], 0, 0, 0);                \
    } } while (0)

#define GEMM_MAIN64(nt) do {                                                  \
    for (int t_ = 0; t_ < (nt); ++t_) {                                       \
        if (t_ > 0) __syncthreads();                                          \
        STAGE64(t_);                                                          \
        __syncthreads();                                                      \
        COMPUTE64;                                                            \
    } } while (0)

__device__ inline void topk_reduce_store(float top[KTOP], float (*buf)[KTOP], int t,
                                         float* feat, int q, int c0) {
    #pragma unroll
    for (int i = 0; i < KTOP; ++i) buf[t][i] = top[i];
    __syncthreads();
    for (int stride = 128; stride >= 1; stride >>= 1) {
        if (t < stride) {
            float arr[KTOP];
            #pragma unroll
            for (int i = 0; i < KTOP; ++i) arr[i] = buf[t][i];
            #pragma unroll
            for (int r = 0; r < KTOP; ++r) { float v = buf[t + stride][r]; INSERT5(arr, v); }
            #pragma unroll
            for (int i = 0; i < KTOP; ++i) buf[t][i] = arr[i];
        }
        __syncthreads();
    }
    if (t == 0) {
        float mx = buf[0][0];
        float sum = buf[0][0] + buf[0][1] + buf[0][2] + buf[0][3] + buf[0][4];
        feat[(long)q * 8 + c0] = mx;
        feat[(long)q * 8 + c0 + 1] = sum / (float)KTOP;
    }
}

// ------- shared sim GEMM body with fused top-5 pool (C[d][q] = D @ Q^T) -------
struct SimSlice { const short* D; const short* Q; const float* dssq; const float* qssq;
                  const int* dtok; int mask; };

__device__ void sim_body(SimSlice sl, int x, int dblk, int sslot,
                         const int* qtok, float* part, char* AsB, char* BsB) {
    int m0 = dblk * 64, n0 = x * 128;
    const int ldbB = STRB;
    GEMM_PRELUDE64
    const char* Ab = (const char*)sl.D + (size_t)m0 * STRB;
    const char* Bb = (const char*)sl.Q + (size_t)n0 * STRB;

    f32x4 acc[2][4] = {};
    GEMM_MAIN64(5);

    float dinvv[2][4];
    int dtokv[2][4];
    #pragma unroll
    for (int mf = 0; mf < 2; ++mf) {
        int r0 = m0 + wr * 32 + mf * 16 + (lane >> 4) * 4;
        float4 dv = *(const float4*)(sl.dssq + r0);
        dinvv[mf][0] = rsqrtf(dv.x); dinvv[mf][1] = rsqrtf(dv.y);
        dinvv[mf][2] = rsqrtf(dv.z); dinvv[mf][3] = rsqrtf(dv.w);
        if (sl.mask) {
            int4 tv = *(const int4*)(sl.dtok + r0);
            dtokv[mf][0] = tv.x; dtokv[mf][1] = tv.y; dtokv[mf][2] = tv.z; dtokv[mf][3] = tv.w;
        }
    }
    __syncthreads();
    float (*lds5)[128][KTOP] = (float (*)[128][KTOP])AsB;

    #pragma unroll
    for (int nf = 0; nf < 4; ++nf) {
        int c = n0 + wc * 64 + nf * 16 + (lane & 15);
        float qs = rsqrtf(sl.qssq[c]);
        bool qok = sl.mask ? (qtok[c] > 1) : true;
        float top[KTOP];
        #pragma unroll
        for (int i = 0; i < KTOP; ++i) top[i] = -3.4e38f;
        #pragma unroll
        for (int mf = 0; mf < 2; ++mf)
            #pragma unroll
            for (int j = 0; j < 4; ++j) {
                float v = acc[mf][nf][j] * qs * dinvv[mf][j];
                if (sl.mask && (!qok || dtokv[mf][j] <= 1)) v = 0.f;
                INSERT5(top, v);
            }
        #pragma unroll
        for (int st = 16; st <= 32; st <<= 1) {
            float o[KTOP];
            #pragma unroll
            for (int i = 0; i < KTOP; ++i) o[i] = __shfl_xor(top[i], st, 64);
            #pragma unroll
            for (int i = 0; i < KTOP; ++i) { float v = o[i]; INSERT5(top, v); }
        }
        if (lane < 16) {
            int ql = wc * 64 + nf * 16 + lane;
            #pragma unroll
            for (int i = 0; i < KTOP; ++i) lds5[wr][ql][i] = top[i];
        }
    }
    __syncthreads();
    if (tid < 128) {
        float arr[KTOP];
        #pragma unroll
        for (int i = 0; i < KTOP; ++i) arr[i] = lds5[0][tid][i];
        #pragma unroll
        for (int i = 0; i < KTOP; ++i) { float v = lds5[1][tid][i]; INSERT5(arr, v); }
        int q = n0 + tid;
        float* dst = part + ((size_t)(sslot * 128 + dblk) * QLEN + q) * KTOP;
        #pragma unroll
        for (int i = 0; i < KTOP; ++i) dst[i] = arr[i];
    }
}

// ============ conv_oh: conv GEMMs + oh partial pools + embedding sims, one launch ======
// blocks [0,1560): conv (swizzled); [1560,1816): oh partials; [1816,2328): sim_e
struct ConvSlice { const short* A; const short* F; short* O; float* ssq;
                   const float* alpha; int fs; int shift; };
struct ConvOhArgs { ConvSlice s[6]; const float* S1; const float* S2; float* part;
                    SimSlice se[2]; const int* qtok; };

__global__ __launch_bounds__(256) void conv_oh(ConvOhArgs args) {
    __shared__ char smem[24576];
    int orig = blockIdx.x;
    if (orig >= 1560) {
        int r2 = orig - 1560;
        if (r2 < 256) {
            // ---- oh partial pool: doc = r2>>7, dblk = r2&127 (64 rows each) ----
            int doc = r2 >> 7, dblk = r2 & 127;
            const float* S = doc == 0 ? args.S1 : args.S2;
            int t = threadIdx.x;
            const float* base = S + (size_t)dblk * 64 * QLEN + t;
            float top[KTOP];
            #pragma unroll
            for (int i = 0; i < KTOP; ++i) top[i] = -3.4e38f;
            float vb[16];
            #pragma unroll
            for (int g = 0; g < 4; ++g) {
                #pragma unroll
                for (int j = 0; j < 16; ++j)
                    vb[j] = base[(size_t)(g * 16 + j) * QLEN];
                #pragma unroll
                for (int j = 0; j < 16; ++j) INSERT5(top, vb[j]);
            }
            float* dst = args.part + ((size_t)((6 + doc) * 128 + dblk) * QLEN + t) * KTOP;
            #pragma unroll
            for (int i = 0; i < KTOP; ++i) dst[i] = top[i];
        } else {
            // ---- embedding sims (independent of conv): slices 0 and 3 ----
            int e = r2 - 256;
            int which = e >> 8;          // 0 -> slice0 (d1), 1 -> slice3 (d2)
            int rem = e & 255;
            int x = rem & 1, dblk = rem >> 1;
            sim_body(args.se[which], x, dblk, which == 0 ? 0 : 3,
                     args.qtok, args.part, smem, smem + 8192);
        }
        return;
    }
    int lin = orig;
    int o = (lin & 7) * 195 + (lin >> 3);   // bijective XCD swizzle (1560 = 8*195)
    int z;
    if (o < 12) { z = 0; }
    else if (o < 24) { z = 1; o -= 12; }
    else { o -= 24; z = 2 + o / 384; o -= (z - 2) * 384; }
    ConvSlice sl;
    switch (z) {
        case 0: sl = args.s[0]; break; case 1: sl = args.s[1]; break;
        case 2: sl = args.s[2]; break; case 3: sl = args.s[3]; break;
        case 4: sl = args.s[4]; break; default: sl = args.s[5]; break;
    }
    int x = o % 3, y = o / 3;
    int m0 = y * 64, n0 = x * 128;
    int ldbB = sl.fs * STRB;

    char* AsB = smem;
    char* BsB = smem + 8192;
    GEMM_PRELUDE64
    const char* Ab = (const char*)sl.A + (size_t)(m0 + sl.shift) * STRB;
    const char* Bb = (const char*)sl.F + (size_t)n0 * ldbB;
    int nt = sl.fs * 5;
    float al = *sl.alpha;

    f32x4 acc[2][4] = {};
    GEMM_MAIN64(nt);

    #pragma unroll
    for (int mf = 0; mf < 2; ++mf) {
        #pragma unroll
        for (int j = 0; j < 4; ++j) {
            int r = m0 + wr * 32 + mf * 16 + (lane >> 4) * 4 + j;
            float p = 0.f;
            #pragma unroll
            for (int nf = 0; nf < 4; ++nf) {
                int c = n0 + wc * 64 + nf * 16 + (lane & 15);
                short ov = 0;
                if (c < EMB) {
                    float v = acc[mf][nf][j];
                    v = v >= 0.f ? v : al * v;
                    v += bf2f(sl.A[(size_t)r * STR + c]);
                    ov = f2bf(v);
                    p += v * v;
                }
                if (c < STR) sl.O[(size_t)r * STR + c] = ov;
            }
            p += __shfl_xor(p, 1, 64);
            p += __shfl_xor(p, 2, 64);
            p += __shfl_xor(p, 4, 64);
            p += __shfl_xor(p, 8, 64);
            if ((lane & 15) == 0) atomicAdd(sl.ssq + r, p);
        }
    }
}

// ------- conv-dependent sim GEMMs: slices {1,2,4,5}; 1024 blocks -------
struct SimArgs { SimSlice s[4]; int slot[4]; const int* qtok; float* part; };

__global__ __launch_bounds__(256) void sim_mfma(SimArgs args) {
    int lin = blockIdx.x;
    int wk = (lin & 7) * 128 + (lin >> 3);    // bijective XCD swizzle (1024 = 8*128)
    int si = wk >> 8; int rem = wk & 255; int x = rem & 1; int dblk = rem >> 1;
    SimSlice sl;
    int sslot;
    switch (si) {
        case 0: sl = args.s[0]; sslot = args.slot[0]; break;
        case 1: sl = args.s[1]; sslot = args.slot[1]; break;
        case 2: sl = args.s[2]; sslot = args.slot[2]; break;
        default: sl = args.s[3]; sslot = args.slot[3]; break;
    }
    __shared__ char AsB[8192];
    __shared__ char BsB[16384];
    sim_body(sl, x, dblk, sslot, args.qtok, args.part, AsB, BsB);
}

// final per-q reduce of partials: 8 slices x 128 partials each
// y<6: sim (c0 = 2+2*(y%3)); y=6,7: oh (c0 = 0)
__global__ void pool_reduce(const float* __restrict__ part,
                            float* __restrict__ feat1, float* __restrict__ feat2) {
    int s = blockIdx.y, q = blockIdx.x, t = threadIdx.x;
    __shared__ float buf[256][KTOP];
    float top[KTOP];
    #pragma unroll
    for (int i = 0; i < KTOP; ++i) top[i] = -3.4e38f;
    if (t < 128) {
        const float* src = part + ((size_t)(s * 128 + t) * QLEN + q) * KTOP;
        #pragma unroll
        for (int i = 0; i < KTOP; ++i) { float v = src[i]; INSERT5(top, v); }
    }
    float* feat = (s < 6) ? (s < 3 ? feat1 : feat2) : (s == 6 ? feat1 : feat2);
    int c0 = (s < 6) ? 2 + 2 * (s % 3) : 0;
    topk_reduce_store(top, buf, t, feat, q, c0);
}

// ---------------- final MLP + reduce + loss ----------------
__global__ void final_score(const float* __restrict__ feat1, const float* __restrict__ feat2,
                            const float* __restrict__ w1, const float* __restrict__ b1,
                            const float* __restrict__ w2, const float* __restrict__ b2,
                            const float* __restrict__ a1p, const float* __restrict__ a2p,
                            float* __restrict__ out) {
    __shared__ float s1buf[256], s2buf[256];
    int q = threadIdx.x;
    float a1 = *a1p, a2 = *a2p;
    float v[2];
    #pragma unroll
    for (int dsel = 0; dsel < 2; ++dsel) {
        const float* feat = dsel == 0 ? feat1 : feat2;
        float x[8];
        #pragma unroll
        for (int i = 0; i < 8; ++i) x[i] = feat[q * 8 + i];
        float lo[8];
        #pragma unroll
        for (int j = 0; j < 8; ++j) {
            float s = b1[j];
            #pragma unroll
            for (int i = 0; i < 8; ++i) s += x[i] * w1[j * 8 + i];
            lo[j] = s >= 0.f ? s : a1 * s;
        }
        float s2v = b2[0];
        #pragma unroll
        for (int j = 0; j < 8; ++j) s2v += lo[j] * w2[j];
        v[dsel] = s2v >= 0.f ? s2v : a2 * s2v;
    }
    s1buf[q] = v[0];
    s2buf[q] = v[1];
    __syncthreads();
    for (int st = 128; st >= 1; st >>= 1) {
        if (q < st) { s1buf[q] += s1buf[q + st]; s2buf[q] += s2buf[q + st]; }
        __syncthreads();
    }
    if (q == 0) {
        float d1 = s1buf[0] / (float)QLEN;
        float d2 = s2buf[0] / (float)QLEN;
        float loss1 = fmaxf(0.f, -(d1 - d2) + 0.9f);
        out[0] = loss1; out[1] = d1; out[2] = d2; out[3] = loss1; out[4] = 0.f;
    }
}

extern "C" void kernel_launch(void* const* d_in, const int* in_sizes, int n_in,
                              void* d_out, int out_size, void* d_ws, size_t ws_size,
                              hipStream_t stream) {
    const int*   doc1     = (const int*)d_in[0];
    const int*   doc2     = (const int*)d_in[1];
    const int*   question = (const int*)d_in[2];
    const float* doc1_sim = (const float*)d_in[3];
    const float* doc2_sim = (const float*)d_in[4];
    const float* embeds   = (const float*)d_in[5];
    const float* filt_bi  = (const float*)d_in[6];
    const float* filt_tri = (const float*)d_in[7];
    const float* a_bi     = (const float*)d_in[8];
    const float* a_tri    = (const float*)d_in[9];
    const float* w1       = (const float*)d_in[10];
    const float* b1       = (const float*)d_in[11];
    const float* w2       = (const float*)d_in[12];
    const float* b2       = (const float*)d_in[13];
    const float* a1       = (const float*)d_in[14];
    const float* a2       = (const float*)d_in[15];
    float* out = (float*)d_out;

    float* ws = (float*)d_ws;
    size_t off = 0;
    auto allocf = [&](size_t n) { float* p = ws + off; off += n; return p; };
    float* feat1 = allocf(QLEN * 8);
    float* feat2 = allocf(QLEN * 8);
    float* ssq_qe  = allocf(QLEN);
    float* ssq_d1e = allocf(DLEN);
    float* ssq_d2e = allocf(DLEN);
    float* convssq = allocf(2 * QLEN + 4 * DLEN);   // 33280 floats, 16B-aligned
    float* ssq_qbi  = convssq;
    float* ssq_qtri = convssq + QLEN;
    float* ssq_d1bi  = convssq + 2 * QLEN;
    float* ssq_d1tri = convssq + 2 * QLEN + DLEN;
    float* ssq_d2bi  = convssq + 2 * QLEN + 2 * DLEN;
    float* ssq_d2tri = convssq + 2 * QLEN + 3 * DLEN;
    float* part = allocf((size_t)8 * 128 * QLEN * KTOP);   // 6 sim + 2 oh slices
    off = (off + 7) & ~(size_t)7;

    short* hb = (short*)(ws + off);
    size_t hoff = 0;
    auto alloch = [&](size_t n) { short* p = hb + hoff; hoff += n; return p; };
    const size_t QH = (size_t)(QLEN + 8) * STR;
    const size_t DH = (size_t)(DLEN + 8) * STR;
    short* qe_h   = alloch(QH);
    short* qbi_h  = alloch(QH);
    short* qtri_h = alloch(QH);
    short* d1e_h   = alloch(DH);
    short* d1bi_h  = alloch(DH);
    short* d1tri_h = alloch(DH);
    short* d2e_h   = alloch(DH);
    short* d2bi_h  = alloch(DH);
    short* d2tri_h = alloch(DH);
    short* fbi_h  = alloch((size_t)384 * 2 * STR);
    short* ftri_h = alloch((size_t)384 * 3 * STR);

    // prep: gathers (+norm sumsq), filter casts, convssq zeroing; 4679 blocks
    PrepArgs pa;
    pa.embeds = embeds;
    pa.toks[0] = question; pa.out[0] = qe_h;  pa.ssq[0] = ssq_qe;  pa.rows[0] = QLEN;
    pa.toks[1] = doc1;     pa.out[1] = d1e_h; pa.ssq[1] = ssq_d1e; pa.rows[1] = DLEN;
    pa.toks[2] = doc2;     pa.out[2] = d2e_h; pa.ssq[2] = ssq_d2e; pa.rows[2] = DLEN;
    pa.filt[0] = filt_bi;  pa.fout[0] = fbi_h;
    pa.filt[1] = filt_tri; pa.fout[1] = ftri_h;
    pa.convssq = convssq;
    prep<<<dim3(4679), 256, 0, stream>>>(pa);

    // conv GEMMs (1560) + oh partials (256) + embedding sims (512) in one launch
    ConvOhArgs ca;
    ca.s[0] = { qe_h,  fbi_h,  qbi_h,  ssq_qbi,  a_bi,  2, 1 };
    ca.s[1] = { qe_h,  ftri_h, qtri_h, ssq_qtri, a_tri, 3, 0 };
    ca.s[2] = { d1e_h, fbi_h,  d1bi_h, ssq_d1bi, a_bi,  2, 1 };
    ca.s[3] = { d1e_h, ftri_h, d1tri_h,ssq_d1tri,a_tri, 3, 0 };
    ca.s[4] = { d2e_h, fbi_h,  d2bi_h, ssq_d2bi, a_bi,  2, 1 };
    ca.s[5] = { d2e_h, ftri_h, d2tri_h,ssq_d2tri,a_tri, 3, 0 };
    ca.S1 = doc1_sim; ca.S2 = doc2_sim;
    ca.part = part;
    ca.se[0] = { d1e_h, qe_h, ssq_d1e, ssq_qe, doc1, 1 };
    ca.se[1] = { d2e_h, qe_h, ssq_d2e, ssq_qe, doc2, 1 };
    ca.qtok = question;
    conv_oh<<<dim3(2328), 256, 0, stream>>>(ca);

    // conv-dependent sims: slices {1,2,4,5}; 1024 blocks
    SimArgs sa;
    sa.s[0] = { d1bi_h,  qbi_h,  ssq_d1bi,  ssq_qbi,  doc1, 0 };  sa.slot[0] = 1;
    sa.s[1] = { d1tri_h, qtri_h, ssq_d1tri, ssq_qtri, doc1, 0 };  sa.slot[1] = 2;
    sa.s[2] = { d2bi_h,  qbi_h,  ssq_d2bi,  ssq_qbi,  doc2, 0 };  sa.slot[2] = 4;
    sa.s[3] = { d2tri_h, qtri_h, ssq_d2tri, ssq_qtri, doc2, 0 };  sa.slot[3] = 5;
    sa.qtok = question;
    sa.part = part;
    sim_mfma<<<dim3(1024), 256, 0, stream>>>(sa);

    // fold partials (6 sim + 2 oh) into feature columns
    pool_reduce<<<dim3(QLEN, 8), 256, 0, stream>>>(part, feat1, feat2);

    final_score<<<dim3(1), 256, 0, stream>>>(feat1, feat2, w1, b1, w2, b2, a1, a2, out);
}

// Round 13
// 104.992 us; speedup vs baseline: 1.2989x; 1.2989x over previous
//
#include <hip/hip_runtime.h>

#define EMB   300
#define QLEN  256
#define DLEN  8192
#define KTOP  5
#define STR   320      // bf16 row stride (elements)
#define STRB  640      // bf16 row stride (bytes)

typedef __attribute__((ext_vector_type(8))) short short8v;
typedef __attribute__((ext_vector_type(4))) float f32x4;

__device__ inline float bf2f(short u) {
    return __uint_as_float(((unsigned int)(unsigned short)u) << 16);
}
__device__ inline short f2bf(float f) {
    unsigned int x = __float_as_uint(f);
    unsigned int r = x + 0x7fffu + ((x >> 16) & 1u);  // RNE
    return (short)(r >> 16);
}
__device__ inline void gload_lds16(const void* g, void* l) {
    __builtin_amdgcn_global_load_lds((const __attribute__((address_space(1))) void*)g,
                                     (__attribute__((address_space(3))) void*)l, 16, 0, 0);
}
// LDS swizzle involution on [rows][128B] tiles: XOR 16B-slot bits (4-6) with row&7
__device__ inline int swz128(int a) { return a ^ (((a >> 7) & 7) << 4); }

// ---------------- top-5 insert ----------------
#define INSERT5(arr, v)                                                          \
    if ((v) > arr[4]) {                                                          \
        arr[4] = (v);                                                            \
        if (arr[4] > arr[3]) { float t_ = arr[4]; arr[4] = arr[3]; arr[3] = t_; }\
        if (arr[3] > arr[2]) { float t_ = arr[3]; arr[3] = arr[2]; arr[2] = t_; }\
        if (arr[2] > arr[1]) { float t_ = arr[2]; arr[2] = arr[1]; arr[1] = t_; }\
        if (arr[1] > arr[0]) { float t_ = arr[1]; arr[1] = arr[0]; arr[0] = t_; }\
    }

// ====== prep: gathers (+row sumsq), filter casts, and convssq zeroing, one launch ======
// blocks [0,4646): wave-per-row work; blocks [4646,4679): zero convssq (33280 floats)
struct PrepArgs {
    const float* embeds;
    const int* toks[3]; short* out[3]; float* ssq[3]; int rows[3];
    const float* filt[2]; short* fout[2];
    float* convssq;
};

__global__ void prep(PrepArgs pa) {
    if (blockIdx.x >= 4646) {
        int idx = (blockIdx.x - 4646) * 256 + threadIdx.x;
        if (idx < 8320) {
            float4 z = {0.f, 0.f, 0.f, 0.f};
            *(float4*)(pa.convssq + idx * 4) = z;
        }
        return;
    }
    int W = blockIdx.x * 4 + (threadIdx.x >> 6);
    int lane = threadIdx.x & 63;
    int e0 = lane * 8;
    if (W < 16664) {
        int s, r;
        if (W < 264) { s = 0; r = W; }
        else if (W < 8464) { s = 1; r = W - 264; }
        else { s = 2; r = W - 8464; }
        int rows = pa.rows[s];
        short8v ov = {0, 0, 0, 0, 0, 0, 0, 0};
        float sum = 0.f;
        if (r < rows && e0 < 300) {
            const float* src = pa.embeds + (long)pa.toks[s][r] * EMB;
            float4 f0 = *(const float4*)(src + e0);
            ov[0] = f2bf(f0.x); ov[1] = f2bf(f0.y); ov[2] = f2bf(f0.z); ov[3] = f2bf(f0.w);
            sum = f0.x * f0.x + f0.y * f0.y + f0.z * f0.z + f0.w * f0.w;
            if (e0 < 296) {
                float4 f1 = *(const float4*)(src + e0 + 4);
                ov[4] = f2bf(f1.x); ov[5] = f2bf(f1.y); ov[6] = f2bf(f1.z); ov[7] = f2bf(f1.w);
                sum += f1.x * f1.x + f1.y * f1.y + f1.z * f1.z + f1.w * f1.w;
            }
        }
        if (e0 < STR) *(short8v*)(pa.out[s] + (long)r * STR + e0) = ov;
        #pragma unroll
        for (int off = 32; off > 0; off >>= 1) sum += __shfl_down(sum, off, 64);
        if (lane == 0 && r < rows) pa.ssq[s][r] = sum;
    } else {
        int w2 = W - 16664;
        int s = (w2 < 768) ? 0 : 1;
        int R = (s == 0) ? w2 : w2 - 768;
        int o = (s == 0) ? (R >> 1) : (R / 3);
        short8v ov = {0, 0, 0, 0, 0, 0, 0, 0};
        if (o < EMB && e0 < 300) {
            const float* src = pa.filt[s] + (long)R * EMB;
            float4 f0 = *(const float4*)(src + e0);
            ov[0] = f2bf(f0.x); ov[1] = f2bf(f0.y); ov[2] = f2bf(f0.z); ov[3] = f2bf(f0.w);
            if (e0 < 296) {
                float4 f1 = *(const float4*)(src + e0 + 4);
                ov[4] = f2bf(f1.x); ov[5] = f2bf(f1.y); ov[6] = f2bf(f1.z); ov[7] = f2bf(f1.w);
            }
        }
        if (e0 < STR) *(short8v*)(pa.fout[s] + (long)R * STR + e0) = ov;
    }
}

// ============ single-buffer BK=64 MFMA GEMM core, 64x128 tile, 4 waves (2x2 of 32x64) ======
#define GEMM_PRELUDE64                                                        \
    int tid = threadIdx.x, lane = tid & 63, w = tid >> 6;                     \
    int wr = w >> 1, wc = w & 1;                                              \
    int arow[2], acol[2], brow[4], bcol[4];                                   \
    _Pragma("unroll")                                                         \
    for (int i_ = 0; i_ < 2; ++i_) {                                          \
        int lg_ = swz128(w * 2048 + i_ * 1024 + lane * 16);                   \
        arow[i_] = lg_ >> 7; acol[i_] = lg_ & 127;                            \
    }                                                                         \
    _Pragma("unroll")                                                         \
    for (int i_ = 0; i_ < 4; ++i_) {                                          \
        int lg_ = swz128(w * 4096 + i_ * 1024 + lane * 16);                   \
        brow[i_] = lg_ >> 7; bcol[i_] = lg_ & 127;                            \
    }

#define STAGE64(t) do { int kb_ = (t) * 128;                                  \
    _Pragma("unroll")                                                         \
    for (int i_ = 0; i_ < 2; ++i_)                                            \
        gload_lds16(Ab + (size_t)arow[i_] * STRB + kb_ + acol[i_],            \
                    AsB + w * 2048 + i_ * 1024);                              \
    _Pragma("unroll")                                                         \
    for (int i_ = 0; i_ < 4; ++i_)                                            \
        gload_lds16(Bb + (size_t)brow[i_] * ldbB + kb_ + bcol[i_],            \
                    BsB + w * 4096 + i_ * 1024);                              \
    } while (0)

#define COMPUTE64 do {                                                        \
    _Pragma("unroll")                                                         \
    for (int h_ = 0; h_ < 2; ++h_) {                                          \
        short8v a_[2], b_[4];                                                 \
        _Pragma("unroll")                                                     \
        for (int f_ = 0; f_ < 2; ++f_) {                                      \
            int la_ = (wr * 32 + f_ * 16 + (lane & 15)) * 128                 \
                      + ((lane >> 4) << 4) + h_ * 64;                         \
            a_[f_] = *(const short8v*)(AsB + swz128(la_));                    \
        }                                                                     \
        _Pragma("unroll")                                                     \
        for (int f_ = 0; f_ < 4; ++f_) {                                      \
            int lb_ = (wc * 64 + f_ * 16 + (lane & 15)) * 128                 \
                      + ((lane >> 4) << 4) + h_ * 64;                         \
            b_[f_] = *(const short8v*)(BsB + swz128(lb_));                    \
        }                                                                     \
        _Pragma("unroll")                                                     \
        for (int mf_ = 0; mf_ < 2; ++mf_)                                     \
            _Pragma("unroll")                                                 \
            for (int nf_ = 0; nf_ < 4; ++nf_)                                 \
                acc[mf_][nf_] = __builtin_amdgcn_mfma_f32_16x16x32_bf16(      \
                    a_[mf_], b_[nf_], acc[mf_][nf_], 0, 0, 0);                \
    } } while (0)

#define GEMM_MAIN64(nt) do {                                                  \
    for (int t_ = 0; t_ < (nt); ++t_) {                                       \
        if (t_ > 0) __syncthreads();                                          \
        STAGE64(t_);                                                          \
        __syncthreads();                                                      \
        COMPUTE64;                                                            \
    } } while (0)

__device__ inline void topk_reduce_store(float top[KTOP], float (*buf)[KTOP], int t,
                                         float* feat, int q, int c0) {
    #pragma unroll
    for (int i = 0; i < KTOP; ++i) buf[t][i] = top[i];
    __syncthreads();
    for (int stride = 128; stride >= 1; stride >>= 1) {
        if (t < stride) {
            float arr[KTOP];
            #pragma unroll
            for (int i = 0; i < KTOP; ++i) arr[i] = buf[t][i];
            #pragma unroll
            for (int r = 0; r < KTOP; ++r) { float v = buf[t + stride][r]; INSERT5(arr, v); }
            #pragma unroll
            for (int i = 0; i < KTOP; ++i) buf[t][i] = arr[i];
        }
        __syncthreads();
    }
    if (t == 0) {
        float mx = buf[0][0];
        float sum = buf[0][0] + buf[0][1] + buf[0][2] + buf[0][3] + buf[0][4];
        feat[(long)q * 8 + c0] = mx;
        feat[(long)q * 8 + c0 + 1] = sum / (float)KTOP;
    }
}

// ============ conv_oh: conv GEMMs (tri-first worklist) + oh partial pools ======
// blocks [0,1560): conv (swizzled, fs=3 slices first); [1560,1816): oh partials.
struct ConvSlice { const short* A; const short* F; short* O; float* ssq;
                   const float* alpha; int fs; int shift; };
struct ConvOhArgs { ConvSlice s[6]; const float* S1; const float* S2; float* part; };

__global__ __launch_bounds__(256) void conv_oh(ConvOhArgs args) {
    int orig = blockIdx.x;
    if (orig >= 1560) {
        // ---- oh partial pool: r2 in [0,256): doc = r2>>7, dblk = r2&127 (64 rows) ----
        int r2 = orig - 1560;
        int doc = r2 >> 7, dblk = r2 & 127;
        const float* S = doc == 0 ? args.S1 : args.S2;
        int t = threadIdx.x;
        const float* base = S + (size_t)dblk * 64 * QLEN + t;
        float top[KTOP];
        #pragma unroll
        for (int i = 0; i < KTOP; ++i) top[i] = -3.4e38f;
        float vb[16];
        #pragma unroll
        for (int g = 0; g < 4; ++g) {
            #pragma unroll
            for (int j = 0; j < 16; ++j)
                vb[j] = base[(size_t)(g * 16 + j) * QLEN];
            #pragma unroll
            for (int j = 0; j < 16; ++j) INSERT5(top, vb[j]);
        }
        float* dst = args.part + ((size_t)((6 + doc) * 128 + dblk) * QLEN + t) * KTOP;
        #pragma unroll
        for (int i = 0; i < KTOP; ++i) dst[i] = top[i];
        return;
    }
    int lin = orig;
    int o = (lin & 7) * 195 + (lin >> 3);   // bijective XCD swizzle (1560 = 8*195)
    // tri-first worklist: [0,384) d1tri; [384,768) d2tri; [768,780) qtri;
    //                     [780,1164) d1bi; [1164,1548) d2bi; [1548,1560) qbi
    int z;
    if (o < 384) { z = 3; }
    else if (o < 768) { z = 5; o -= 384; }
    else if (o < 780) { z = 1; o -= 768; }
    else if (o < 1164) { z = 2; o -= 780; }
    else if (o < 1548) { z = 4; o -= 1164; }
    else { z = 0; o -= 1548; }
    ConvSlice sl;
    switch (z) {
        case 0: sl = args.s[0]; break; case 1: sl = args.s[1]; break;
        case 2: sl = args.s[2]; break; case 3: sl = args.s[3]; break;
        case 4: sl = args.s[4]; break; default: sl = args.s[5]; break;
    }
    int x = o % 3, y = o / 3;
    int m0 = y * 64, n0 = x * 128;
    int ldbB = sl.fs * STRB;

    __shared__ char smem[24576];
    char* AsB = smem;
    char* BsB = smem + 8192;
    GEMM_PRELUDE64
    const char* Ab = (const char*)sl.A + (size_t)(m0 + sl.shift) * STRB;
    const char* Bb = (const char*)sl.F + (size_t)n0 * ldbB;
    int nt = sl.fs * 5;
    float al = *sl.alpha;

    f32x4 acc[2][4] = {};
    GEMM_MAIN64(nt);

    #pragma unroll
    for (int mf = 0; mf < 2; ++mf) {
        #pragma unroll
        for (int j = 0; j < 4; ++j) {
            int r = m0 + wr * 32 + mf * 16 + (lane >> 4) * 4 + j;
            float p = 0.f;
            #pragma unroll
            for (int nf = 0; nf < 4; ++nf) {
                int c = n0 + wc * 64 + nf * 16 + (lane & 15);
                short ov = 0;
                if (c < EMB) {
                    float v = acc[mf][nf][j];
                    v = v >= 0.f ? v : al * v;
                    v += bf2f(sl.A[(size_t)r * STR + c]);
                    ov = f2bf(v);
                    p += v * v;
                }
                if (c < STR) sl.O[(size_t)r * STR + c] = ov;
            }
            p += __shfl_xor(p, 1, 64);
            p += __shfl_xor(p, 2, 64);
            p += __shfl_xor(p, 4, 64);
            p += __shfl_xor(p, 8, 64);
            if ((lane & 15) == 0) atomicAdd(sl.ssq + r, p);
        }
    }
}

// ------- sim GEMM with fused top-5 pool (C[d][q] = D @ Q^T); all 6 slices -------
struct SimSlice { const short* D; const short* Q; const float* dssq; const float* qssq;
                  const int* dtok; int mask; };
struct SimArgs { SimSlice s[6]; const int* qtok; float* part; };

__global__ __launch_bounds__(256) void sim_mfma(SimArgs args) {
    int lin = blockIdx.x;
    int wk = (lin & 7) * 192 + (lin >> 3);    // bijective XCD swizzle (1536 = 8*192)
    int s = wk >> 8; int rem = wk & 255; int x = rem & 1; int dblk = rem >> 1;
    SimSlice sl;
    switch (s) {
        case 0: sl = args.s[0]; break; case 1: sl = args.s[1]; break;
        case 2: sl = args.s[2]; break; case 3: sl = args.s[3]; break;
        case 4: sl = args.s[4]; break; default: sl = args.s[5]; break;
    }
    int m0 = dblk * 64, n0 = x * 128;
    const int ldbB = STRB;

    __shared__ char AsB[8192];
    __shared__ char BsB[16384];
    GEMM_PRELUDE64
    const char* Ab = (const char*)sl.D + (size_t)m0 * STRB;
    const char* Bb = (const char*)sl.Q + (size_t)n0 * STRB;

    f32x4 acc[2][4] = {};
    GEMM_MAIN64(5);

    // ---- fused pool epilogue ----
    float dinvv[2][4];
    int dtokv[2][4];
    #pragma unroll
    for (int mf = 0; mf < 2; ++mf) {
        int r0 = m0 + wr * 32 + mf * 16 + (lane >> 4) * 4;
        float4 dv = *(const float4*)(sl.dssq + r0);
        dinvv[mf][0] = rsqrtf(dv.x); dinvv[mf][1] = rsqrtf(dv.y);
        dinvv[mf][2] = rsqrtf(dv.z); dinvv[mf][3] = rsqrtf(dv.w);
        if (sl.mask) {
            int4 tv = *(const int4*)(sl.dtok + r0);
            dtokv[mf][0] = tv.x; dtokv[mf][1] = tv.y; dtokv[mf][2] = tv.z; dtokv[mf][3] = tv.w;
        }
    }
    __syncthreads();
    float (*lds5)[128][KTOP] = (float (*)[128][KTOP])AsB;

    #pragma unroll
    for (int nf = 0; nf < 4; ++nf) {
        int c = n0 + wc * 64 + nf * 16 + (lane & 15);
        float qs = rsqrtf(sl.qssq[c]);
        bool qok = sl.mask ? (args.qtok[c] > 1) : true;
        float top[KTOP];
        #pragma unroll
        for (int i = 0; i < KTOP; ++i) top[i] = -3.4e38f;
        #pragma unroll
        for (int mf = 0; mf < 2; ++mf)
            #pragma unroll
            for (int j = 0; j < 4; ++j) {
                float v = acc[mf][nf][j] * qs * dinvv[mf][j];
                if (sl.mask && (!qok || dtokv[mf][j] <= 1)) v = 0.f;
                INSERT5(top, v);
            }
        #pragma unroll
        for (int st = 16; st <= 32; st <<= 1) {
            float o[KTOP];
            #pragma unroll
            for (int i = 0; i < KTOP; ++i) o[i] = __shfl_xor(top[i], st, 64);
            #pragma unroll
            for (int i = 0; i < KTOP; ++i) { float v = o[i]; INSERT5(top, v); }
        }
        if (lane < 16) {
            int ql = wc * 64 + nf * 16 + lane;
            #pragma unroll
            for (int i = 0; i < KTOP; ++i) lds5[wr][ql][i] = top[i];
        }
    }
    __syncthreads();
    if (tid < 128) {
        float arr[KTOP];
        #pragma unroll
        for (int i = 0; i < KTOP; ++i) arr[i] = lds5[0][tid][i];
        #pragma unroll
        for (int i = 0; i < KTOP; ++i) { float v = lds5[1][tid][i]; INSERT5(arr, v); }
        int q = n0 + tid;
        float* dst = args.part + ((size_t)(s * 128 + dblk) * QLEN + q) * KTOP;
        #pragma unroll
        for (int i = 0; i < KTOP; ++i) dst[i] = arr[i];
    }
}

// final per-q reduce of partials: 8 slices x 128 partials each
// y<6: sim (c0 = 2+2*(y%3)); y=6,7: oh (c0 = 0)
__global__ void pool_reduce(const float* __restrict__ part,
                            float* __restrict__ feat1, float* __restrict__ feat2) {
    int s = blockIdx.y, q = blockIdx.x, t = threadIdx.x;
    __shared__ float buf[256][KTOP];
    float top[KTOP];
    #pragma unroll
    for (int i = 0; i < KTOP; ++i) top[i] = -3.4e38f;
    if (t < 128) {
        const float* src = part + ((size_t)(s * 128 + t) * QLEN + q) * KTOP;
        #pragma unroll
        for (int i = 0; i < KTOP; ++i) { float v = src[i]; INSERT5(top, v); }
    }
    float* feat = (s < 6) ? (s < 3 ? feat1 : feat2) : (s == 6 ? feat1 : feat2);
    int c0 = (s < 6) ? 2 + 2 * (s % 3) : 0;
    topk_reduce_store(top, buf, t, feat, q, c0);
}

// ---------------- final MLP + reduce + loss ----------------
__global__ void final_score(const float* __restrict__ feat1, const float* __restrict__ feat2,
                            const float* __restrict__ w1, const float* __restrict__ b1,
                            const float* __restrict__ w2, const float* __restrict__ b2,
                            const float* __restrict__ a1p, const float* __restrict__ a2p,
                            float* __restrict__ out) {
    __shared__ float s1buf[256], s2buf[256];
    int q = threadIdx.x;
    float a1 = *a1p, a2 = *a2p;
    float v[2];
    #pragma unroll
    for (int dsel = 0; dsel < 2; ++dsel) {
        const float* feat = dsel == 0 ? feat1 : feat2;
        float x[8];
        #pragma unroll
        for (int i = 0; i < 8; ++i) x[i] = feat[q * 8 + i];
        float lo[8];
        #pragma unroll
        for (int j = 0; j < 8; ++j) {
            float s = b1[j];
            #pragma unroll
            for (int i = 0; i < 8; ++i) s += x[i] * w1[j * 8 + i];
            lo[j] = s >= 0.f ? s : a1 * s;
        }
        float s2v = b2[0];
        #pragma unroll
        for (int j = 0; j < 8; ++j) s2v += lo[j] * w2[j];
        v[dsel] = s2v >= 0.f ? s2v : a2 * s2v;
    }
    s1buf[q] = v[0];
    s2buf[q] = v[1];
    __syncthreads();
    for (int st = 128; st >= 1; st >>= 1) {
        if (q < st) { s1buf[q] += s1buf[q + st]; s2buf[q] += s2buf[q + st]; }
        __syncthreads();
    }
    if (q == 0) {
        float d1 = s1buf[0] / (float)QLEN;
        float d2 = s2buf[0] / (float)QLEN;
        float loss1 = fmaxf(0.f, -(d1 - d2) + 0.9f);
        out[0] = loss1; out[1] = d1; out[2] = d2; out[3] = loss1; out[4] = 0.f;
    }
}

extern "C" void kernel_launch(void* const* d_in, const int* in_sizes, int n_in,
                              void* d_out, int out_size, void* d_ws, size_t ws_size,
                              hipStream_t stream) {
    const int*   doc1     = (const int*)d_in[0];
    const int*   doc2     = (const int*)d_in[1];
    const int*   question = (const int*)d_in[2];
    const float* doc1_sim = (const float*)d_in[3];
    const float* doc2_sim = (const float*)d_in[4];
    const float* embeds   = (const float*)d_in[5];
    const float* filt_bi  = (const float*)d_in[6];
    const float* filt_tri = (const float*)d_in[7];
    const float* a_bi     = (const float*)d_in[8];
    const float* a_tri    = (const float*)d_in[9];
    const float* w1       = (const float*)d_in[10];
    const float* b1       = (const float*)d_in[11];
    const float* w2       = (const float*)d_in[12];
    const float* b2       = (const float*)d_in[13];
    const float* a1       = (const float*)d_in[14];
    const float* a2       = (const float*)d_in[15];
    float* out = (float*)d_out;

    float* ws = (float*)d_ws;
    size_t off = 0;
    auto allocf = [&](size_t n) { float* p = ws + off; off += n; return p; };
    float* feat1 = allocf(QLEN * 8);
    float* feat2 = allocf(QLEN * 8);
    float* ssq_qe  = allocf(QLEN);
    float* ssq_d1e = allocf(DLEN);
    float* ssq_d2e = allocf(DLEN);
    float* convssq = allocf(2 * QLEN + 4 * DLEN);   // 33280 floats, 16B-aligned
    float* ssq_qbi  = convssq;
    float* ssq_qtri = convssq + QLEN;
    float* ssq_d1bi  = convssq + 2 * QLEN;
    float* ssq_d1tri = convssq + 2 * QLEN + DLEN;
    float* ssq_d2bi  = convssq + 2 * QLEN + 2 * DLEN;
    float* ssq_d2tri = convssq + 2 * QLEN + 3 * DLEN;
    float* part = allocf((size_t)8 * 128 * QLEN * KTOP);   // 6 sim + 2 oh slices
    off = (off + 7) & ~(size_t)7;

    short* hb = (short*)(ws + off);
    size_t hoff = 0;
    auto alloch = [&](size_t n) { short* p = hb + hoff; hoff += n; return p; };
    const size_t QH = (size_t)(QLEN + 8) * STR;
    const size_t DH = (size_t)(DLEN + 8) * STR;
    short* qe_h   = alloch(QH);
    short* qbi_h  = alloch(QH);
    short* qtri_h = alloch(QH);
    short* d1e_h   = alloch(DH);
    short* d1bi_h  = alloch(DH);
    short* d1tri_h = alloch(DH);
    short* d2e_h   = alloch(DH);
    short* d2bi_h  = alloch(DH);
    short* d2tri_h = alloch(DH);
    short* fbi_h  = alloch((size_t)384 * 2 * STR);
    short* ftri_h = alloch((size_t)384 * 3 * STR);

    // prep: gathers (+norm sumsq), filter casts, convssq zeroing; 4679 blocks
    PrepArgs pa;
    pa.embeds = embeds;
    pa.toks[0] = question; pa.out[0] = qe_h;  pa.ssq[0] = ssq_qe;  pa.rows[0] = QLEN;
    pa.toks[1] = doc1;     pa.out[1] = d1e_h; pa.ssq[1] = ssq_d1e; pa.rows[1] = DLEN;
    pa.toks[2] = doc2;     pa.out[2] = d2e_h; pa.ssq[2] = ssq_d2e; pa.rows[2] = DLEN;
    pa.filt[0] = filt_bi;  pa.fout[0] = fbi_h;
    pa.filt[1] = filt_tri; pa.fout[1] = ftri_h;
    pa.convssq = convssq;
    prep<<<dim3(4679), 256, 0, stream>>>(pa);

    // conv GEMMs (1560, tri-first) + oh partials (256) in one launch
    ConvOhArgs ca;
    ca.s[0] = { qe_h,  fbi_h,  qbi_h,  ssq_qbi,  a_bi,  2, 1 };
    ca.s[1] = { qe_h,  ftri_h, qtri_h, ssq_qtri, a_tri, 3, 0 };
    ca.s[2] = { d1e_h, fbi_h,  d1bi_h, ssq_d1bi, a_bi,  2, 1 };
    ca.s[3] = { d1e_h, ftri_h, d1tri_h,ssq_d1tri,a_tri, 3, 0 };
    ca.s[4] = { d2e_h, fbi_h,  d2bi_h, ssq_d2bi, a_bi,  2, 1 };
    ca.s[5] = { d2e_h, ftri_h, d2tri_h,ssq_d2tri,a_tri, 3, 0 };
    ca.S1 = doc1_sim; ca.S2 = doc2_sim;
    ca.part = part;
    conv_oh<<<dim3(1816), 256, 0, stream>>>(ca);

    // all 6 sim GEMMs with fused pooling; 1536 blocks
    SimArgs sa;
    sa.s[0] = { d1e_h,   qe_h,   ssq_d1e,   ssq_qe,   doc1, 1 };
    sa.s[1] = { d1bi_h,  qbi_h,  ssq_d1bi,  ssq_qbi,  doc1, 0 };
    sa.s[2] = { d1tri_h, qtri_h, ssq_d1tri, ssq_qtri, doc1, 0 };
    sa.s[3] = { d2e_h,   qe_h,   ssq_d2e,   ssq_qe,   doc2, 1 };
    sa.s[4] = { d2bi_h,  qbi_h,  ssq_d2bi,  ssq_qbi,  doc2, 0 };
    sa.s[5] = { d2tri_h, qtri_h, ssq_d2tri, ssq_qtri, doc2, 0 };
    sa.qtok = question;
    sa.part = part;
    sim_mfma<<<dim3(1536), 256, 0, stream>>>(sa);

    // fold partials (6 sim + 2 oh) into feature columns
    pool_reduce<<<dim3(QLEN, 8), 256, 0, stream>>>(part, feat1, feat2);

    final_score<<<dim3(1), 256, 0, stream>>>(feat1, feat2, w1, b1, w2, b2, a1, a2, out);
}